// Round 1
// baseline (140.179 us; speedup 1.0000x reference)
//
#include <hip/hip_runtime.h>
#include <hip/hip_bf16.h>

typedef __attribute__((ext_vector_type(8))) short bf16x8;
typedef __attribute__((ext_vector_type(4))) float f32x4;

#define B_NODES   50000
#define K_NEIGH   32
#define D_DIM     128
#define LDS_STRIDE 136   // bf16 elems per LDS row: 272 B = 17*16 (16B-aligned, conflict-free b128 reads)

__global__ __launch_bounds__(256, 3) void aggr_pool_kernel(
    const float* __restrict__ features,
    const float* __restrict__ W,
    const float* __restrict__ bias,
    const int*  __restrict__ neigh_idx,
    float* __restrict__ out)
{
    __shared__ __hip_bfloat16 WT[D_DIM * LDS_STRIDE];   // W^T as bf16: WT[e][k] = W[k][e]

    const int tid = threadIdx.x;

    // ---- stage W^T into LDS as bf16 (once per workgroup) ----
    {
        const int e = tid & 127;
        const int h = tid >> 7;            // 0/1: which half of k-range
        for (int i = 0; i < 32; ++i) {
            const int k = (h * 32 + i) * 2;
            float2 w;
            w.x = W[k * D_DIM + e];
            w.y = W[(k + 1) * D_DIM + e];
            *reinterpret_cast<__hip_bfloat162*>(&WT[e * LDS_STRIDE + k]) =
                __float22bfloat162_rn(w);
        }
    }
    __syncthreads();

    const int lane = tid & 63;
    const int wid  = tid >> 6;
    const int i16  = lane & 15;
    const int g    = lane >> 4;            // 0..3 (k-group)

    // bias for columns nt*16 + i16
    float bcol[8];
#pragma unroll
    for (int nt = 0; nt < 8; ++nt) bcol[nt] = bias[nt * 16 + i16];

    const int stride = gridDim.x * 4;
    for (int node = blockIdx.x * 4 + wid; node < B_NODES; node += stride) {
        // 32 neighbor indices for this node live in lanes 0..31
        int idxv = 0;
        if (lane < K_NEIGH) idxv = neigh_idx[node * K_NEIGH + lane];

        // ---- gather A-fragments straight from global in MFMA layout ----
        // A-frag (16x16x32 bf16): lane holds A[l&15][s*32 + (l>>4)*8 + j], j=0..7
        bf16x8 afrag[2][4];
#pragma unroll
        for (int mt = 0; mt < 2; ++mt) {
            const int row = __shfl(idxv, mt * 16 + i16);
            const float* p = features + (size_t)row * D_DIM + g * 8;
#pragma unroll
            for (int s = 0; s < 4; ++s) {
                const float4 a0 = *reinterpret_cast<const float4*>(p + s * 32);
                const float4 a1 = *reinterpret_cast<const float4*>(p + s * 32 + 4);
                union { bf16x8 v; __hip_bfloat162 h2[4]; } cv;
                cv.h2[0] = __float22bfloat162_rn(float2{a0.x, a0.y});
                cv.h2[1] = __float22bfloat162_rn(float2{a0.z, a0.w});
                cv.h2[2] = __float22bfloat162_rn(float2{a1.x, a1.y});
                cv.h2[3] = __float22bfloat162_rn(float2{a1.z, a1.w});
                afrag[mt][s] = cv.v;
            }
        }

        // ---- 8 N-tiles of 16 cols: z = X*W, max over 32 rows, +b, sigmoid ----
#pragma unroll 2
        for (int nt = 0; nt < 8; ++nt) {
            f32x4 acc0 = {0.f, 0.f, 0.f, 0.f};
            f32x4 acc1 = {0.f, 0.f, 0.f, 0.f};
#pragma unroll
            for (int s = 0; s < 4; ++s) {
                // B-frag: lane holds B[s*32 + (l>>4)*8 + j][nt*16 + (l&15)] = WT[col][k..k+7]
                const bf16x8 bfrag = *reinterpret_cast<const bf16x8*>(
                    &WT[(nt * 16 + i16) * LDS_STRIDE + s * 32 + g * 8]);
                acc0 = __builtin_amdgcn_mfma_f32_16x16x32_bf16(afrag[0][s], bfrag, acc0, 0, 0, 0);
                acc1 = __builtin_amdgcn_mfma_f32_16x16x32_bf16(afrag[1][s], bfrag, acc1, 0, 0, 0);
            }
            // lane holds z[g*4+j][col] (acc0) and z[16+g*4+j][col] (acc1), col = i16
            float pm = fmaxf(fmaxf(fmaxf(acc0.x, acc0.y), fmaxf(acc0.z, acc0.w)),
                             fmaxf(fmaxf(acc1.x, acc1.y), fmaxf(acc1.z, acc1.w)));
            pm = fmaxf(pm, __shfl_xor(pm, 16));
            pm = fmaxf(pm, __shfl_xor(pm, 32));   // all lanes: max over 32 neighbors
            const float v = 1.0f / (1.0f + __expf(-(pm + bcol[nt])));
            if (lane < 16) out[(size_t)node * D_DIM + nt * 16 + lane] = v;
        }
    }
}

extern "C" void kernel_launch(void* const* d_in, const int* in_sizes, int n_in,
                              void* d_out, int out_size, void* d_ws, size_t ws_size,
                              hipStream_t stream) {
    const float* features = (const float*)d_in[0];
    const float* W        = (const float*)d_in[1];
    const float* bias     = (const float*)d_in[2];
    const int*   neigh    = (const int*)d_in[3];
    float* out = (float*)d_out;

    dim3 grid(768), block(256);
    hipLaunchKernelGGL(aggr_pool_kernel, grid, block, 0, stream,
                       features, W, bias, neigh, out);
}